// Round 1
// baseline (5248.106 us; speedup 1.0000x reference)
//
#include <hip/hip_runtime.h>
#include <hip/hip_bf16.h>

#define VOCABSZ 32000
#define D 128
#define HEADS 8
#define DKH 16
#define DFF 512
#define NLAYER 4
#define NCLS 10
#define NN 131072
#define NLEAF 65536
#define ETOT 655360
#define NREAD 4096

typedef unsigned short u16;
typedef unsigned int u32;

__device__ __forceinline__ float b2f(u16 u){ u32 x = ((u32)u)<<16; return __builtin_bit_cast(float, x); }
__device__ __forceinline__ u16 f2b(float f){ u32 i = __builtin_bit_cast(u32, f); u32 r = (i + 0x7FFFu + ((i>>16)&1u))>>16; return (u16)r; }

__device__ __forceinline__ float wredsum(float v){
  v += __shfl_xor(v,32); v += __shfl_xor(v,16); v += __shfl_xor(v,8);
  v += __shfl_xor(v,4);  v += __shfl_xor(v,2);  v += __shfl_xor(v,1);
  return v;
}

// ---------------- leaf embedding + LN (one 64-lane wave per row, 2 dims/lane) ----------
__global__ __launch_bounds__(256) void k_embed(const int* __restrict__ x, const int* __restrict__ pos,
    const int* __restrict__ leaf, const float* __restrict__ emb,
    const float* __restrict__ g, const float* __restrict__ b, float* __restrict__ h){
  int row = blockIdx.x*4 + (threadIdx.x>>6);
  int lane = threadIdx.x & 63;
  int tok = x[row]; float p = (float)pos[row];
  float v[2];
  #pragma unroll
  for(int j=0;j<2;j++){
    int d = lane + 64*j;
    float freq = expf(-0.07195578515529633f * (float)(d & ~1));
    float ang = p * freq;
    float pe = (d&1) ? cosf(ang) : sinf(ang);
    v[j] = emb[(size_t)tok*D + d] * 11.313708498984761f + pe;
  }
  float mean = wredsum(v[0]+v[1]) * (1.0f/128.0f);
  float d0 = v[0]-mean, d1 = v[1]-mean;
  float var = wredsum(d0*d0 + d1*d1) * (1.0f/128.0f);
  float rs = rsqrtf(var + 1e-5f);
  size_t orow = (size_t)leaf[row];
  h[orow*D + lane]      = d0*rs*g[lane]      + b[lane];
  h[orow*D + lane + 64] = d1*rs*g[lane+64]   + b[lane+64];
}

// ---------------- CSR build: count -> scan -> scatter ----------------
__global__ __launch_bounds__(256) void k_count(const int* __restrict__ dst, int* __restrict__ cnt){
  int e = blockIdx.x*256 + threadIdx.x;
  atomicAdd(&cnt[dst[e]], 1);
}

__global__ __launch_bounds__(1024) void k_scan(int* __restrict__ cnt, int* __restrict__ indptr){
  __shared__ int s[1024];
  int tid = threadIdx.x; int base = 0;
  for(int ch=0; ch<NN/1024; ch++){
    int i = ch*1024 + tid;
    int v = cnt[i];
    s[tid] = v; __syncthreads();
    for(int off=1; off<1024; off<<=1){
      int t = (tid>=off) ? s[tid-off] : 0;
      __syncthreads();
      s[tid] += t;
      __syncthreads();
    }
    int excl = s[tid] - v;
    indptr[i] = base + excl;
    cnt[i]    = base + excl;   // becomes the scatter cursor
    int tot = s[1023];
    __syncthreads();
    base += tot;
  }
  if(tid==0) indptr[NN] = base;
}

__global__ __launch_bounds__(256) void k_scatter(const int* __restrict__ src, const int* __restrict__ dst,
    int* __restrict__ cursor, int* __restrict__ esrc){
  int e = blockIdx.x*256 + threadIdx.x;
  int p = atomicAdd(&cursor[dst[e]], 1);
  esrc[p] = src[e];
}

// ---------------- fused QKV GEMM: 64-row tile, h staged once, 3 weights looped -------
__global__ __launch_bounds__(256) void k_qkv(const float* __restrict__ h,
    const float* __restrict__ Wq, const float* __restrict__ bq,
    const float* __restrict__ Wk, const float* __restrict__ bk,
    const float* __restrict__ Wv, const float* __restrict__ bv,
    u16* __restrict__ qb, u16* __restrict__ kb, u16* __restrict__ vb){
  __shared__ float As[64][132];
  __shared__ u16  Bs[128][132];
  const int tid = threadIdx.x;
  const size_t r0 = (size_t)blockIdx.x * 64;
  {
    const float4* hp = (const float4*)(h + r0*D);
    #pragma unroll
    for(int t=0;t<8;t++){
      int idx = tid + t*256; int r = idx>>5, c = idx&31;
      float4 f = hp[idx];
      As[r][c*4+0]=f.x; As[r][c*4+1]=f.y; As[r][c*4+2]=f.z; As[r][c*4+3]=f.w;
    }
  }
  const float* W[3]    = {Wq,Wk,Wv};
  const float* bias[3] = {bq,bk,bv};
  u16* outp[3] = {qb,kb,vb};
  const int tc = tid & 15, tr = tid >> 4;
  for(int w=0; w<3; w++){
    __syncthreads();
    {
      const float4* wp = (const float4*)W[w];
      #pragma unroll
      for(int t=0;t<16;t++){
        int idx = tid + t*256; int r = idx>>5, c = idx&31;
        float4 f = wp[idx];
        u16* dp = &Bs[r][c*4];
        dp[0]=f2b(f.x); dp[1]=f2b(f.y); dp[2]=f2b(f.z); dp[3]=f2b(f.w);
      }
    }
    __syncthreads();
    float acc[4][8];
    #pragma unroll
    for(int j=0;j<8;j++){ float bj = bias[w][tc*8+j];
      #pragma unroll
      for(int i=0;i<4;i++) acc[i][j] = bj; }
    #pragma unroll 4
    for(int k=0;k<128;k++){
      float a0=As[tr*4+0][k], a1=As[tr*4+1][k], a2=As[tr*4+2][k], a3=As[tr*4+3][k];
      ushort4 u0 = *(const ushort4*)&Bs[k][tc*8];
      ushort4 u1 = *(const ushort4*)&Bs[k][tc*8+4];
      float bvec[8] = {b2f(u0.x),b2f(u0.y),b2f(u0.z),b2f(u0.w),b2f(u1.x),b2f(u1.y),b2f(u1.z),b2f(u1.w)};
      #pragma unroll
      for(int j=0;j<8;j++){
        acc[0][j] = fmaf(a0, bvec[j], acc[0][j]);
        acc[1][j] = fmaf(a1, bvec[j], acc[1][j]);
        acc[2][j] = fmaf(a2, bvec[j], acc[2][j]);
        acc[3][j] = fmaf(a3, bvec[j], acc[3][j]);
      }
    }
    #pragma unroll
    for(int i=0;i<4;i++){
      size_t row = r0 + tr*4 + i;
      uint4 pk;
      pk.x = (u32)f2b(acc[i][0]) | ((u32)f2b(acc[i][1])<<16);
      pk.y = (u32)f2b(acc[i][2]) | ((u32)f2b(acc[i][3])<<16);
      pk.z = (u32)f2b(acc[i][4]) | ((u32)f2b(acc[i][5])<<16);
      pk.w = (u32)f2b(acc[i][6]) | ((u32)f2b(acc[i][7])<<16);
      *(uint4*)(outp[w] + row*D + tc*8) = pk;
    }
  }
}

// ---------------- per-node edge attention, online softmax (128 thr/node) -------------
__global__ __launch_bounds__(256) void k_attn(const u16* __restrict__ qb, const u16* __restrict__ kb,
    const u16* __restrict__ vb, const int* __restrict__ indptr, const int* __restrict__ esrc,
    float* __restrict__ agg){
  int node = blockIdx.x*2 + (threadIdx.x>>7);
  int d = threadIdx.x & 127;
  int beg = indptr[node], end = indptr[node+1];
  float qd = b2f(qb[(size_t)node*D + d]) * 0.25f;   // fold 1/sqrt(DK)
  float m = -3.0e38f, den = 0.f, acc = 0.f;
  for(int e=beg; e<end; e++){
    int s = esrc[e];
    float kd = b2f(kb[(size_t)s*D + d]);
    float vd = b2f(vb[(size_t)s*D + d]);
    float p = qd*kd;
    p += __shfl_xor(p,1); p += __shfl_xor(p,2); p += __shfl_xor(p,4); p += __shfl_xor(p,8);
    float nm = fmaxf(m, p);
    float fs = __expf(m - nm);
    float w  = __expf(p - nm);
    den = den*fs + w;
    acc = acc*fs + w*vd;
    m = nm;
  }
  agg[(size_t)node*D + d] = acc/den;
}

// ---------------- O-projection + bias + residual + LN1, h updated in place -----------
__global__ __launch_bounds__(256) void k_owo(const float* __restrict__ agg,
    const float* __restrict__ Wo, const float* __restrict__ bo,
    const float* __restrict__ g1, const float* __restrict__ b1,
    float* __restrict__ h){
  __shared__ float As[64][132];
  __shared__ u16  Bs[128][132];
  const int tid = threadIdx.x;
  const size_t r0 = (size_t)blockIdx.x * 64;
  {
    const float4* ap = (const float4*)(agg + r0*D);
    #pragma unroll
    for(int t=0;t<8;t++){
      int idx = tid + t*256; int r = idx>>5, c = idx&31;
      float4 f = ap[idx];
      As[r][c*4+0]=f.x; As[r][c*4+1]=f.y; As[r][c*4+2]=f.z; As[r][c*4+3]=f.w;
    }
    const float4* wp = (const float4*)Wo;
    #pragma unroll
    for(int t=0;t<16;t++){
      int idx = tid + t*256; int r = idx>>5, c = idx&31;
      float4 f = wp[idx];
      u16* dp = &Bs[r][c*4];
      dp[0]=f2b(f.x); dp[1]=f2b(f.y); dp[2]=f2b(f.z); dp[3]=f2b(f.w);
    }
  }
  __syncthreads();
  const int tc = tid & 15, tr = tid >> 4;
  float acc[4][8];
  #pragma unroll
  for(int j=0;j<8;j++){ float bj = bo[tc*8+j];
    #pragma unroll
    for(int i=0;i<4;i++) acc[i][j] = bj; }
  #pragma unroll 4
  for(int k=0;k<128;k++){
    float a0=As[tr*4+0][k], a1=As[tr*4+1][k], a2=As[tr*4+2][k], a3=As[tr*4+3][k];
    ushort4 u0 = *(const ushort4*)&Bs[k][tc*8];
    ushort4 u1 = *(const ushort4*)&Bs[k][tc*8+4];
    float bvec[8] = {b2f(u0.x),b2f(u0.y),b2f(u0.z),b2f(u0.w),b2f(u1.x),b2f(u1.y),b2f(u1.z),b2f(u1.w)};
    #pragma unroll
    for(int j=0;j<8;j++){
      acc[0][j] = fmaf(a0, bvec[j], acc[0][j]);
      acc[1][j] = fmaf(a1, bvec[j], acc[1][j]);
      acc[2][j] = fmaf(a2, bvec[j], acc[2][j]);
      acc[3][j] = fmaf(a3, bvec[j], acc[3][j]);
    }
  }
  __syncthreads();   // everyone done reading As
  #pragma unroll
  for(int i=0;i<4;i++)
    #pragma unroll
    for(int j=0;j<8;j++) As[tr*4+i][tc*8+j] = acc[i][j];
  __syncthreads();
  const int lane = tid & 63, wv = tid >> 6;
  for(int it=0; it<16; it++){
    int rl = it*4 + wv; size_t row = r0 + rl;
    float v0 = As[rl][lane]    + h[row*D + lane];
    float v1 = As[rl][lane+64] + h[row*D + lane + 64];
    float mean = wredsum(v0+v1) * (1.0f/128.0f);
    float d0 = v0-mean, d1 = v1-mean;
    float var = wredsum(d0*d0 + d1*d1) * (1.0f/128.0f);
    float rs = rsqrtf(var + 1e-5f);
    h[row*D + lane]      = d0*rs*g1[lane]    + b1[lane];
    h[row*D + lane + 64] = d1*rs*g1[lane+64] + b1[lane+64];
  }
}

// ---------------- FFN: chunked over DFF, fused relu + residual + LN2 ------------------
__global__ __launch_bounds__(256) void k_ffn(
    const float* __restrict__ W1, const float* __restrict__ b1,
    const float* __restrict__ W2, const float* __restrict__ b2,
    const float* __restrict__ g2, const float* __restrict__ bb2,
    float* __restrict__ h){
  __shared__ float As[64][132];   // h tile (also residual source)
  __shared__ u16  Bs[128][132];   // weight chunk; reused as f32 o-tile at the end
  __shared__ u16  Ts[64][132];    // relu intermediate (bf16)
  const int tid = threadIdx.x;
  const size_t r0 = (size_t)blockIdx.x * 64;
  const int tc = tid & 15, tr = tid >> 4;
  {
    const float4* hp = (const float4*)(h + r0*D);
    #pragma unroll
    for(int t=0;t<8;t++){
      int idx = tid + t*256; int r = idx>>5, c = idx&31;
      float4 f = hp[idx];
      As[r][c*4+0]=f.x; As[r][c*4+1]=f.y; As[r][c*4+2]=f.z; As[r][c*4+3]=f.w;
    }
  }
  float out[4][8];
  #pragma unroll
  for(int j=0;j<8;j++){ float bj = b2[tc*8+j];
    #pragma unroll
    for(int i=0;i<4;i++) out[i][j] = bj; }
  for(int c=0;c<4;c++){
    __syncthreads();
    #pragma unroll
    for(int t=0;t<16;t++){
      int idx = tid + t*256; int r = idx>>5, cc = idx&31;
      float4 f = *(const float4*)(W1 + (size_t)r*DFF + c*128 + cc*4);
      u16* dp = &Bs[r][cc*4];
      dp[0]=f2b(f.x); dp[1]=f2b(f.y); dp[2]=f2b(f.z); dp[3]=f2b(f.w);
    }
    __syncthreads();
    float tacc[4][8];
    #pragma unroll
    for(int j=0;j<8;j++){ float bj = b1[c*128 + tc*8+j];
      #pragma unroll
      for(int i=0;i<4;i++) tacc[i][j] = bj; }
    #pragma unroll 2
    for(int k=0;k<128;k++){
      float a0=As[tr*4+0][k], a1=As[tr*4+1][k], a2=As[tr*4+2][k], a3=As[tr*4+3][k];
      ushort4 u0 = *(const ushort4*)&Bs[k][tc*8];
      ushort4 u1 = *(const ushort4*)&Bs[k][tc*8+4];
      float bvec[8] = {b2f(u0.x),b2f(u0.y),b2f(u0.z),b2f(u0.w),b2f(u1.x),b2f(u1.y),b2f(u1.z),b2f(u1.w)};
      #pragma unroll
      for(int j=0;j<8;j++){
        tacc[0][j] = fmaf(a0, bvec[j], tacc[0][j]);
        tacc[1][j] = fmaf(a1, bvec[j], tacc[1][j]);
        tacc[2][j] = fmaf(a2, bvec[j], tacc[2][j]);
        tacc[3][j] = fmaf(a3, bvec[j], tacc[3][j]);
      }
    }
    #pragma unroll
    for(int i=0;i<4;i++){
      ushort4 p0, p1;
      p0.x=f2b(fmaxf(tacc[i][0],0.f)); p0.y=f2b(fmaxf(tacc[i][1],0.f));
      p0.z=f2b(fmaxf(tacc[i][2],0.f)); p0.w=f2b(fmaxf(tacc[i][3],0.f));
      p1.x=f2b(fmaxf(tacc[i][4],0.f)); p1.y=f2b(fmaxf(tacc[i][5],0.f));
      p1.z=f2b(fmaxf(tacc[i][6],0.f)); p1.w=f2b(fmaxf(tacc[i][7],0.f));
      *(ushort4*)&Ts[tr*4+i][tc*8]   = p0;
      *(ushort4*)&Ts[tr*4+i][tc*8+4] = p1;
    }
    __syncthreads();
    #pragma unroll
    for(int t=0;t<16;t++){
      int idx = tid + t*256; int r = idx>>5, cc = idx&31;
      float4 f = *(const float4*)(W2 + ((size_t)(c*128+r))*D + cc*4);
      u16* dp = &Bs[r][cc*4];
      dp[0]=f2b(f.x); dp[1]=f2b(f.y); dp[2]=f2b(f.z); dp[3]=f2b(f.w);
    }
    __syncthreads();
    #pragma unroll 2
    for(int k=0;k<128;k++){
      float a0=b2f(Ts[tr*4+0][k]), a1=b2f(Ts[tr*4+1][k]), a2=b2f(Ts[tr*4+2][k]), a3=b2f(Ts[tr*4+3][k]);
      ushort4 u0 = *(const ushort4*)&Bs[k][tc*8];
      ushort4 u1 = *(const ushort4*)&Bs[k][tc*8+4];
      float bvec[8] = {b2f(u0.x),b2f(u0.y),b2f(u0.z),b2f(u0.w),b2f(u1.x),b2f(u1.y),b2f(u1.z),b2f(u1.w)};
      #pragma unroll
      for(int j=0;j<8;j++){
        out[0][j] = fmaf(a0, bvec[j], out[0][j]);
        out[1][j] = fmaf(a1, bvec[j], out[1][j]);
        out[2][j] = fmaf(a2, bvec[j], out[2][j]);
        out[3][j] = fmaf(a3, bvec[j], out[3][j]);
      }
    }
  }
  __syncthreads();
  float* Of = (float*)&Bs[0][0];   // 64x132 f32 fits exactly in Bs (33792 B)
  #pragma unroll
  for(int i=0;i<4;i++)
    #pragma unroll
    for(int j=0;j<8;j++) Of[(tr*4+i)*132 + tc*8+j] = out[i][j];
  __syncthreads();
  const int lane = tid & 63, wv = tid >> 6;
  for(int it=0; it<16; it++){
    int rl = it*4 + wv; size_t row = r0 + rl;
    float v0 = Of[rl*132 + lane]      + As[rl][lane];
    float v1 = Of[rl*132 + lane + 64] + As[rl][lane+64];
    float mean = wredsum(v0+v1) * (1.0f/128.0f);
    float d0 = v0-mean, d1 = v1-mean;
    float var = wredsum(d0*d0 + d1*d1) * (1.0f/128.0f);
    float rs = rsqrtf(var + 1e-5f);
    h[row*D + lane]      = d0*rs*g2[lane]    + bb2[lane];
    h[row*D + lane + 64] = d1*rs*g2[lane+64] + bb2[lane+64];
  }
}

// ---------------- readout: gather + 128->10 GEMV + log_softmax (wave per row) ---------
__global__ __launch_bounds__(64) void k_readout(const float* __restrict__ h, const int* __restrict__ rid,
    const float* __restrict__ gw, const float* __restrict__ gb, float* __restrict__ out){
  int r = blockIdx.x; int lane = threadIdx.x;
  size_t node = (size_t)rid[r];
  float h0v = h[node*D + lane], h1v = h[node*D + 64 + lane];
  float lg[NCLS];
  #pragma unroll
  for(int c=0;c<NCLS;c++){
    float p = h0v*gw[lane*NCLS + c] + h1v*gw[(lane+64)*NCLS + c];
    lg[c] = wredsum(p) + gb[c];
  }
  float mx = lg[0];
  #pragma unroll
  for(int c=1;c<NCLS;c++) mx = fmaxf(mx, lg[c]);
  float se = 0.f;
  #pragma unroll
  for(int c=0;c<NCLS;c++) se += expf(lg[c]-mx);
  float lse = mx + logf(se);
  if(lane < NCLS) out[(size_t)r*NCLS + lane] = lg[lane] - lse;
}

extern "C" void kernel_launch(void* const* d_in, const int* in_sizes, int n_in,
                              void* d_out, int out_size, void* d_ws, size_t ws_size,
                              hipStream_t stream) {
  const int* x    = (const int*)d_in[0];
  const int* pos  = (const int*)d_in[1];
  const int* leaf = (const int*)d_in[2];
  const int* src  = (const int*)d_in[3];
  const int* dst  = (const int*)d_in[4];
  const int* rid  = (const int*)d_in[5];
  const float* h0 = (const float*)d_in[6];
  const float* emb= (const float*)d_in[7];
  const float* eng= (const float*)d_in[8];
  const float* enb= (const float*)d_in[9];
  const float* Wq = (const float*)d_in[10];
  const float* bq = (const float*)d_in[11];
  const float* Wk = (const float*)d_in[12];
  const float* bk = (const float*)d_in[13];
  const float* Wv = (const float*)d_in[14];
  const float* bv = (const float*)d_in[15];
  const float* Wo = (const float*)d_in[16];
  const float* bo = (const float*)d_in[17];
  const float* l1g= (const float*)d_in[18];
  const float* l1b= (const float*)d_in[19];
  const float* W1 = (const float*)d_in[20];
  const float* b1 = (const float*)d_in[21];
  const float* W2 = (const float*)d_in[22];
  const float* b2 = (const float*)d_in[23];
  const float* l2g= (const float*)d_in[24];
  const float* l2b= (const float*)d_in[25];
  const float* gw = (const float*)d_in[26];
  const float* gb = (const float*)d_in[27];
  float* out = (float*)d_out;

  char* ws = (char*)d_ws;
  float* h    = (float*)(ws);                               // 67,108,864 B
  float* agg  = (float*)(ws + 67108864);                    // 67,108,864 B
  u16*   qb   = (u16*)  (ws + 134217728);                   // 33,554,432 B
  u16*   kb   = (u16*)  (ws + 167772160);                   // 33,554,432 B
  u16*   vb   = (u16*)  (ws + 201326592);                   // 33,554,432 B
  int*   indptr = (int*)(ws + 234881024);                   // (NN+1)*4 -> 524,544 B
  int*   cursor = (int*)(ws + 234881024 + 524544);          // NN*4 = 524,288 B
  int*   esrc   = (int*)(ws + 234881024 + 524544 + 524288); // ETOT*4 = 2,621,440 B
  // total ~238.6 MB

  hipMemcpyAsync(h, h0, (size_t)NN*D*sizeof(float), hipMemcpyDeviceToDevice, stream);
  k_embed<<<NLEAF/4, 256, 0, stream>>>(x, pos, leaf, emb, eng, enb, h);

  hipMemsetAsync(cursor, 0, NN*sizeof(int), stream);
  k_count  <<<ETOT/256, 256, 0, stream>>>(dst, cursor);
  k_scan   <<<1, 1024, 0, stream>>>(cursor, indptr);
  k_scatter<<<ETOT/256, 256, 0, stream>>>(src, dst, cursor, esrc);

  for(int l=0; l<NLAYER; l++){
    k_qkv<<<NN/64, 256, 0, stream>>>(h, Wq + (size_t)l*D*D, bq + l*D,
                                        Wk + (size_t)l*D*D, bk + l*D,
                                        Wv + (size_t)l*D*D, bv + l*D, qb, kb, vb);
    k_attn<<<NN/2, 256, 0, stream>>>(qb, kb, vb, indptr, esrc, agg);
    k_owo<<<NN/64, 256, 0, stream>>>(agg, Wo + (size_t)l*D*D, bo + l*D,
                                      l1g + l*D, l1b + l*D, h);
    k_ffn<<<NN/64, 256, 0, stream>>>(W1 + (size_t)l*D*DFF, b1 + l*DFF,
                                     W2 + (size_t)l*DFF*D, b2 + l*D,
                                     l2g + l*D, l2b + l*D, h);
  }
  k_readout<<<NREAD, 64, 0, stream>>>(h, rid, gw, gb, out);
}

// Round 2
// 1727.330 us; speedup vs baseline: 3.0383x; 3.0383x over previous
//
#include <hip/hip_runtime.h>
#include <hip/hip_bf16.h>

#define D 128
#define DFF 512
#define NLAYER 4
#define NCLS 10
#define NN 131072
#define NLEAF 65536
#define ETOT 655360
#define NREAD 4096

typedef unsigned short u16;
typedef unsigned int u32;
typedef __attribute__((ext_vector_type(8))) short bf16x8;
typedef __attribute__((ext_vector_type(16))) float f32x16;

#define MFMA32(a,b,c) __builtin_amdgcn_mfma_f32_32x32x16_bf16(a,b,c,0,0,0)

__device__ __forceinline__ float b2f(u16 u){ u32 x = ((u32)u)<<16; return __builtin_bit_cast(float, x); }
__device__ __forceinline__ u16 f2b(float f){ u32 i = __builtin_bit_cast(u32, f); u32 r = (i + 0x7FFFu + ((i>>16)&1u))>>16; return (u16)r; }

__device__ __forceinline__ float wredsum(float v){
  v += __shfl_xor(v,32); v += __shfl_xor(v,16); v += __shfl_xor(v,8);
  v += __shfl_xor(v,4);  v += __shfl_xor(v,2);  v += __shfl_xor(v,1);
  return v;
}
__device__ __forceinline__ float rsum32(float v){
  v += __shfl_xor(v,1); v += __shfl_xor(v,2); v += __shfl_xor(v,4);
  v += __shfl_xor(v,8); v += __shfl_xor(v,16);
  return v;
}

// swizzled LDS tile: byte = row*256 + (bytecol ^ ((row&7)<<4)), 16B granular
__device__ __forceinline__ bf16x8 ldfrag(const u16* buf, int row, int kbyte){
  return *(const bf16x8*)((const char*)buf + row*256 + ((u32)kbyte ^ (u32)((row&7)<<4)));
}

// stage a 128-row x 128-col bf16 tile into swizzled LDS (256 threads, 8 uint4 each)
template<int NROWS>
__device__ __forceinline__ void stage_swz(const u16* __restrict__ src, int rowStrideElems,
                                          int colOffElems, u16* dst, int tid){
  #pragma unroll
  for(int t=0; t<NROWS/16; t++){
    int idx = tid + t*256;
    int row = idx >> 4, slot = idx & 15;
    uint4 v = *(const uint4*)(src + (size_t)row*rowStrideElems + colOffElems + slot*8);
    *(uint4*)((char*)dst + row*256 + (u32)((slot*16) ^ ((row&7)<<4))) = v;
  }
}

// per-wave: 32 rows x 128 cols of C for a 128x128x128 tile (32x32x16 bf16 MFMA)
__device__ __forceinline__ void mfma_row32(const u16* As, const u16* Bs, int wrow0,
                                           int l31, int lkh, f32x16 acc[4]){
  #pragma unroll
  for(int kk=0;kk<8;kk++){
    bf16x8 af = ldfrag(As, wrow0 + l31, kk*32 + lkh);
    #pragma unroll
    for(int c=0;c<4;c++){
      bf16x8 bf = ldfrag(Bs, c*32 + l31, kk*32 + lkh);
      acc[c] = MFMA32(af, bf, acc[c]);
    }
  }
}

// fused residual + LayerNorm epilogue; acc holds proj output (+bias preloaded)
__device__ __forceinline__ void ln_epilogue(f32x16 acc[4], size_t r0, int wrow0, int l31, int h5,
    const float* g, const float* b, float* h, u16* hb){
  float gc[4], bc[4];
  #pragma unroll
  for(int c=0;c<4;c++){ int col = c*32 + l31; gc[c]=g[col]; bc[c]=b[col]; }
  #pragma unroll
  for(int r=0;r<16;r++){
    int rowl = wrow0 + (r&3) + 8*(r>>2) + 4*h5;
    size_t base = (r0 + rowl)*(size_t)D;
    float v[4];
    #pragma unroll
    for(int c=0;c<4;c++) v[c] = acc[c][r] + h[base + c*32 + l31];
    float s = rsum32(v[0]+v[1]+v[2]+v[3]);
    float mean = s * (1.0f/128.0f);
    float dd[4]; float q = 0.f;
    #pragma unroll
    for(int c=0;c<4;c++){ dd[c]=v[c]-mean; q += dd[c]*dd[c]; }
    q = rsum32(q);
    float rs = rsqrtf(q*(1.0f/128.0f) + 1e-5f);
    #pragma unroll
    for(int c=0;c<4;c++){
      float o = dd[c]*rs*gc[c] + bc[c];
      h[base + c*32 + l31] = o;
      hb[base + c*32 + l31] = f2b(o);
    }
  }
}

// ---------------- h0 -> h (f32) + hb (bf16) ----------------
__global__ __launch_bounds__(256) void k_hinit(const float* __restrict__ h0, float* __restrict__ h,
                                               u16* __restrict__ hb){
  int i = blockIdx.x*256 + threadIdx.x;
  float4 v = ((const float4*)h0)[i];
  ((float4*)h)[i] = v;
  ushort4 p; p.x=f2b(v.x); p.y=f2b(v.y); p.z=f2b(v.z); p.w=f2b(v.w);
  ((ushort4*)hb)[i] = p;
}

// ---------------- leaf embedding + LN ----------------
__global__ __launch_bounds__(256) void k_embed(const int* __restrict__ x, const int* __restrict__ pos,
    const int* __restrict__ leaf, const float* __restrict__ emb,
    const float* __restrict__ g, const float* __restrict__ b, float* __restrict__ h,
    u16* __restrict__ hb){
  int row = blockIdx.x*4 + (threadIdx.x>>6);
  int lane = threadIdx.x & 63;
  int tok = x[row]; float p = (float)pos[row];
  float v[2];
  #pragma unroll
  for(int j=0;j<2;j++){
    int d = lane + 64*j;
    float freq = expf(-0.07195578515529633f * (float)(d & ~1));
    float ang = p * freq;
    float pe = (d&1) ? cosf(ang) : sinf(ang);
    v[j] = emb[(size_t)tok*D + d] * 11.313708498984761f + pe;
  }
  float mean = wredsum(v[0]+v[1]) * (1.0f/128.0f);
  float d0 = v[0]-mean, d1 = v[1]-mean;
  float var = wredsum(d0*d0 + d1*d1) * (1.0f/128.0f);
  float rs = rsqrtf(var + 1e-5f);
  size_t orow = (size_t)leaf[row];
  float o0 = d0*rs*g[lane]      + b[lane];
  float o1 = d1*rs*g[lane+64]   + b[lane+64];
  h[orow*D + lane]       = o0;  hb[orow*D + lane]      = f2b(o0);
  h[orow*D + lane + 64]  = o1;  hb[orow*D + lane + 64] = f2b(o1);
}

// ---------------- weight transpose + bf16 convert ----------------
__global__ __launch_bounds__(256) void k_wconv(const float* __restrict__ Wq, const float* __restrict__ Wk,
    const float* __restrict__ Wv, const float* __restrict__ Wo,
    const float* __restrict__ W1, const float* __restrict__ W2,
    u16* __restrict__ wqt, u16* __restrict__ wkt, u16* __restrict__ wvt, u16* __restrict__ wot,
    u16* __restrict__ w1t, u16* __restrict__ w2t){
  int e = blockIdx.x*256 + threadIdx.x;     // NLAYER*196608 total
  int l = e / 196608, r = e % 196608;
  if(r < 65536){
    int w = r >> 14, i = r & 16383;
    int n = i >> 7, k = i & 127;
    const float* src = (w==0)?Wq:(w==1)?Wk:(w==2)?Wv:Wo;
    u16* dst = (w==0)?wqt:(w==1)?wkt:(w==2)?wvt:wot;
    dst[l*16384 + n*128 + k] = f2b(src[l*16384 + k*128 + n]);
  } else if(r < 131072){
    int i = r - 65536; int n = i >> 7, k = i & 127;      // n in 0..511
    w1t[l*65536 + n*128 + k] = f2b(W1[l*65536 + k*512 + n]);
  } else {
    int i = r - 131072; int n = i >> 9, f = i & 511;     // n in 0..127
    w2t[l*65536 + n*512 + f] = f2b(W2[l*65536 + f*128 + n]);
  }
}

// ---------------- CSR build ----------------
__global__ __launch_bounds__(256) void k_count(const int* __restrict__ dst, int* __restrict__ cnt){
  int e = blockIdx.x*256 + threadIdx.x;
  atomicAdd(&cnt[dst[e]], 1);
}
__global__ __launch_bounds__(256) void k_scan1(const int* __restrict__ cnt, int* __restrict__ part,
                                               int* __restrict__ bsum){
  __shared__ int s[256];
  int tid = threadIdx.x; int i = blockIdx.x*256 + tid;
  int v = cnt[i]; s[tid]=v; __syncthreads();
  for(int off=1; off<256; off<<=1){
    int t=(tid>=off)? s[tid-off]:0; __syncthreads();
    s[tid]+=t; __syncthreads();
  }
  part[i] = s[tid]-v;
  if(tid==255) bsum[blockIdx.x] = s[255];
}
__global__ __launch_bounds__(512) void k_scan2(int* __restrict__ bsum){
  __shared__ int s[512];
  int tid = threadIdx.x;
  int v = bsum[tid]; s[tid] = v; __syncthreads();
  for(int off=1; off<512; off<<=1){
    int t = (tid>=off)? s[tid-off]:0; __syncthreads();
    s[tid] += t; __syncthreads();
  }
  bsum[tid] = s[tid] - v;
}
__global__ __launch_bounds__(256) void k_scan3(const int* __restrict__ part, const int* __restrict__ bsum,
                                               int* __restrict__ indptr, int* __restrict__ cursor){
  int i = blockIdx.x*256 + threadIdx.x;
  int v = part[i] + bsum[i>>8];
  indptr[i] = v; cursor[i] = v;
  if(i==0) indptr[NN] = ETOT;
}
__global__ __launch_bounds__(256) void k_scatter(const int* __restrict__ src, const int* __restrict__ dst,
    int* __restrict__ cursor, int* __restrict__ esrc){
  int e = blockIdx.x*256 + threadIdx.x;
  int p = atomicAdd(&cursor[dst[e]], 1);
  esrc[p] = src[e];
}

// ---------------- fused QKV: 128x128 tile MFMA, bf16 out ----------------
__global__ __launch_bounds__(256) void k_qkv(const u16* __restrict__ hb,
    const u16* __restrict__ wqt, const u16* __restrict__ wkt, const u16* __restrict__ wvt,
    const float* __restrict__ bq, const float* __restrict__ bk, const float* __restrict__ bv,
    u16* __restrict__ qb, u16* __restrict__ kb, u16* __restrict__ vb){
  __shared__ u16 As[128*128];
  __shared__ u16 Bs[128*128];
  int tid = threadIdx.x;
  int lane = tid & 63, wv_ = tid >> 6;
  int l31 = lane & 31, h5 = lane >> 5, lkh = h5*16;
  int wrow0 = wv_*32;
  size_t r0 = (size_t)blockIdx.x * 128;
  stage_swz<128>(hb + r0*D, D, 0, As, tid);
  const u16* wt[3]    = {wqt,wkt,wvt};
  const float* bias[3] = {bq,bk,bv};
  u16* outp[3] = {qb,kb,vb};
  #pragma unroll
  for(int w=0; w<3; w++){
    __syncthreads();
    stage_swz<128>(wt[w], D, 0, Bs, tid);
    __syncthreads();
    f32x16 acc[4];
    #pragma unroll
    for(int c=0;c<4;c++){
      float bb = bias[w][c*32+l31];
      #pragma unroll
      for(int i=0;i<16;i++) acc[c][i] = bb;
    }
    mfma_row32(As, Bs, wrow0, l31, lkh, acc);
    u16* op = outp[w];
    #pragma unroll
    for(int c=0;c<4;c++){
      int col = c*32 + l31;
      #pragma unroll
      for(int r=0;r<16;r++){
        int row = wrow0 + (r&3) + 8*(r>>2) + 4*h5;
        op[(r0+row)*D + col] = f2b(acc[c][r]);
      }
    }
  }
}

// ---------------- per-node edge attention, online softmax, bf16 out (aliases q) -------
__global__ __launch_bounds__(256) void k_attn(const u16* qb, const u16* __restrict__ kb,
    const u16* __restrict__ vb, const int* __restrict__ indptr, const int* __restrict__ esrc,
    u16* aggb){
  int node = blockIdx.x*2 + (threadIdx.x>>7);
  int d = threadIdx.x & 127;
  int beg = indptr[node], end = indptr[node+1];
  float qd = b2f(qb[(size_t)node*D + d]) * 0.25f;   // fold 1/sqrt(DK)
  float m = -3.0e38f, den = 0.f, acc = 0.f;
  for(int e=beg; e<end; e++){
    int s = esrc[e];
    float kd = b2f(kb[(size_t)s*D + d]);
    float vd = b2f(vb[(size_t)s*D + d]);
    float p = qd*kd;
    p += __shfl_xor(p,1); p += __shfl_xor(p,2); p += __shfl_xor(p,4); p += __shfl_xor(p,8);
    float nm = fmaxf(m, p);
    float fs = __expf(m - nm);
    float w  = __expf(p - nm);
    den = den*fs + w;
    acc = acc*fs + w*vd;
    m = nm;
  }
  aggb[(size_t)node*D + d] = f2b(acc/den);
}

// ---------------- O-proj + bias + residual + LN1 ----------------
__global__ __launch_bounds__(256) void k_owo(const u16* __restrict__ aggb, const u16* __restrict__ wot,
    const float* __restrict__ bo, const float* __restrict__ g1, const float* __restrict__ b1,
    float* h, u16* hb){
  __shared__ u16 As[128*128];
  __shared__ u16 Bs[128*128];
  int tid = threadIdx.x;
  int lane = tid & 63, wv_ = tid >> 6;
  int l31 = lane & 31, h5 = lane >> 5, lkh = h5*16;
  int wrow0 = wv_*32;
  size_t r0 = (size_t)blockIdx.x * 128;
  stage_swz<128>(aggb + r0*D, D, 0, As, tid);
  stage_swz<128>(wot, D, 0, Bs, tid);
  __syncthreads();
  f32x16 acc[4];
  #pragma unroll
  for(int c=0;c<4;c++){
    float bb = bo[c*32+l31];
    #pragma unroll
    for(int i=0;i<16;i++) acc[c][i] = bb;
  }
  mfma_row32(As, Bs, wrow0, l31, lkh, acc);
  ln_epilogue(acc, r0, wrow0, l31, h5, g1, b1, h, hb);
}

// ---------------- FFN: chunked over DFF, relu via swizzled LDS, fused LN2 -------------
__global__ __launch_bounds__(256) void k_ffn(const u16* __restrict__ w1t, const u16* __restrict__ w2t,
    const float* __restrict__ b1, const float* __restrict__ b2,
    const float* __restrict__ g2, const float* __restrict__ bb2,
    float* h, u16* hb){
  __shared__ u16 As[128*128];
  __shared__ u16 Bs[128*128];
  __shared__ u16 Ts[128*128];
  int tid = threadIdx.x;
  int lane = tid & 63, wv_ = tid >> 6;
  int l31 = lane & 31, h5 = lane >> 5, lkh = h5*16;
  int wrow0 = wv_*32;
  size_t r0 = (size_t)blockIdx.x * 128;
  stage_swz<128>(hb + r0*D, D, 0, As, tid);
  f32x16 out[4];
  #pragma unroll
  for(int c=0;c<4;c++){
    float bb = b2[c*32+l31];
    #pragma unroll
    for(int i=0;i<16;i++) out[c][i] = bb;
  }
  for(int ch=0; ch<4; ch++){
    __syncthreads();
    stage_swz<128>(w1t + ch*128*D, D, 0, Bs, tid);
    __syncthreads();
    f32x16 tacc[4];
    #pragma unroll
    for(int c=0;c<4;c++){
      float bb = b1[ch*128 + c*32 + l31];
      #pragma unroll
      for(int i=0;i<16;i++) tacc[c][i] = bb;
    }
    mfma_row32(As, Bs, wrow0, l31, lkh, tacc);
    #pragma unroll
    for(int c=0;c<4;c++){
      int tcol = c*32 + l31;
      #pragma unroll
      for(int r=0;r<16;r++){
        int trow = wrow0 + (r&3) + 8*(r>>2) + 4*h5;
        *(u16*)((char*)Ts + trow*256 + (u32)((tcol*2) ^ ((trow&7)<<4))) = f2b(fmaxf(tacc[c][r],0.f));
      }
    }
    __syncthreads();
    stage_swz<128>(w2t, DFF, ch*128, Bs, tid);
    __syncthreads();
    mfma_row32(Ts, Bs, wrow0, l31, lkh, out);
  }
  ln_epilogue(out, r0, wrow0, l31, h5, g2, bb2, h, hb);
}

// ---------------- readout ----------------
__global__ __launch_bounds__(64) void k_readout(const float* __restrict__ h, const int* __restrict__ rid,
    const float* __restrict__ gw, const float* __restrict__ gb, float* __restrict__ out){
  int r = blockIdx.x; int lane = threadIdx.x;
  size_t node = (size_t)rid[r];
  float h0v = h[node*D + lane], h1v = h[node*D + 64 + lane];
  float lg[NCLS];
  #pragma unroll
  for(int c=0;c<NCLS;c++){
    float p = h0v*gw[lane*NCLS + c] + h1v*gw[(lane+64)*NCLS + c];
    lg[c] = wredsum(p) + gb[c];
  }
  float mx = lg[0];
  #pragma unroll
  for(int c=1;c<NCLS;c++) mx = fmaxf(mx, lg[c]);
  float se = 0.f;
  #pragma unroll
  for(int c=0;c<NCLS;c++) se += expf(lg[c]-mx);
  float lse = mx + logf(se);
  if(lane < NCLS) out[(size_t)r*NCLS + lane] = lg[lane] - lse;
}

extern "C" void kernel_launch(void* const* d_in, const int* in_sizes, int n_in,
                              void* d_out, int out_size, void* d_ws, size_t ws_size,
                              hipStream_t stream) {
  const int* x    = (const int*)d_in[0];
  const int* pos  = (const int*)d_in[1];
  const int* leaf = (const int*)d_in[2];
  const int* src  = (const int*)d_in[3];
  const int* dst  = (const int*)d_in[4];
  const int* rid  = (const int*)d_in[5];
  const float* h0 = (const float*)d_in[6];
  const float* emb= (const float*)d_in[7];
  const float* eng= (const float*)d_in[8];
  const float* enb= (const float*)d_in[9];
  const float* Wq = (const float*)d_in[10];
  const float* bq = (const float*)d_in[11];
  const float* Wk = (const float*)d_in[12];
  const float* bk = (const float*)d_in[13];
  const float* Wv = (const float*)d_in[14];
  const float* bv = (const float*)d_in[15];
  const float* Wo = (const float*)d_in[16];
  const float* bo = (const float*)d_in[17];
  const float* l1g= (const float*)d_in[18];
  const float* l1b= (const float*)d_in[19];
  const float* W1 = (const float*)d_in[20];
  const float* b1 = (const float*)d_in[21];
  const float* W2 = (const float*)d_in[22];
  const float* b2 = (const float*)d_in[23];
  const float* l2g= (const float*)d_in[24];
  const float* l2b= (const float*)d_in[25];
  const float* gw = (const float*)d_in[26];
  const float* gb = (const float*)d_in[27];
  float* out = (float*)d_out;

  char* ws = (char*)d_ws;
  float* h    = (float*)(ws);                        // 67,108,864
  u16* hb     = (u16*)(ws + 67108864);               // 33,554,432
  u16* qb     = (u16*)(ws + 100663296);              // 33,554,432 (aliased as agg out)
  u16* kb     = (u16*)(ws + 134217728);              // 33,554,432
  u16* vb     = (u16*)(ws + 167772160);              // 33,554,432
  u16* wqt    = (u16*)(ws + 201326592);              // 131,072
  u16* wkt    = (u16*)(ws + 201457664);
  u16* wvt    = (u16*)(ws + 201588736);
  u16* wot    = (u16*)(ws + 201719808);
  u16* w1t    = (u16*)(ws + 201850880);              // 524,288
  u16* w2t    = (u16*)(ws + 202375168);              // 524,288
  int* indptr = (int*)(ws + 202899456);              // 524,544
  int* cursor = (int*)(ws + 203424000);              // 524,288
  int* part   = (int*)(ws + 203948288);              // 524,288
  int* bsum   = (int*)(ws + 204472576);              // 2,048
  int* esrc   = (int*)(ws + 204474624);              // 2,621,440 -> total ~207.1 MB

  k_hinit<<<NN*D/4/256, 256, 0, stream>>>(h0, h, hb);
  k_embed<<<NLEAF/4, 256, 0, stream>>>(x, pos, leaf, emb, eng, enb, h, hb);
  k_wconv<<<NLAYER*196608/256, 256, 0, stream>>>(Wq,Wk,Wv,Wo,W1,W2, wqt,wkt,wvt,wot,w1t,w2t);

  hipMemsetAsync(cursor, 0, NN*sizeof(int), stream);
  k_count  <<<ETOT/256, 256, 0, stream>>>(dst, cursor);
  k_scan1  <<<NN/256, 256, 0, stream>>>(cursor, part, bsum);
  k_scan2  <<<1, 512, 0, stream>>>(bsum);
  k_scan3  <<<NN/256, 256, 0, stream>>>(part, bsum, indptr, cursor);
  k_scatter<<<ETOT/256, 256, 0, stream>>>(src, dst, cursor, esrc);

  for(int l=0; l<NLAYER; l++){
    k_qkv<<<NN/128, 256, 0, stream>>>(hb, wqt + l*16384, wkt + l*16384, wvt + l*16384,
                                      bq + l*D, bk + l*D, bv + l*D, qb, kb, vb);
    k_attn<<<NN/2, 256, 0, stream>>>(qb, kb, vb, indptr, esrc, qb);
    k_owo<<<NN/128, 256, 0, stream>>>(qb, wot + l*16384, bo + l*D,
                                      l1g + l*D, l1b + l*D, h, hb);
    k_ffn<<<NN/128, 256, 0, stream>>>(w1t + l*65536, w2t + l*65536,
                                      b1 + l*DFF, b2 + l*D, l2g + l*D, l2b + l*D, h, hb);
  }
  k_readout<<<NREAD, 64, 0, stream>>>(h, rid, gw, gb, out);
}

// Round 3
// 969.686 us; speedup vs baseline: 5.4122x; 1.7813x over previous
//
#include <hip/hip_runtime.h>
#include <hip/hip_bf16.h>

#define D 128
#define DFF 512
#define NLAYER 4
#define NCLS 10
#define NN 131072
#define NLEAF 65536
#define ETOT 655360
#define NREAD 4096

typedef unsigned short u16;
typedef unsigned int u32;
typedef __attribute__((ext_vector_type(8))) short bf16x8;
typedef __attribute__((ext_vector_type(16))) float f32x16;

#define MFMA32(a,b,c) __builtin_amdgcn_mfma_f32_32x32x16_bf16(a,b,c,0,0,0)

__device__ __forceinline__ float b2f(u16 u){ u32 x = ((u32)u)<<16; return __builtin_bit_cast(float, x); }
__device__ __forceinline__ u16 f2b(float f){ u32 i = __builtin_bit_cast(u32, f); u32 r = (i + 0x7FFFu + ((i>>16)&1u))>>16; return (u16)r; }
__device__ __forceinline__ float blo(u32 u){ return __builtin_bit_cast(float, u<<16); }
__device__ __forceinline__ float bhi(u32 u){ return __builtin_bit_cast(float, u & 0xffff0000u); }

__device__ __forceinline__ float wredsum(float v){
  v += __shfl_xor(v,32); v += __shfl_xor(v,16); v += __shfl_xor(v,8);
  v += __shfl_xor(v,4);  v += __shfl_xor(v,2);  v += __shfl_xor(v,1);
  return v;
}
__device__ __forceinline__ float rsum32(float v){
  v += __shfl_xor(v,1); v += __shfl_xor(v,2); v += __shfl_xor(v,4);
  v += __shfl_xor(v,8); v += __shfl_xor(v,16);
  return v;
}

// swizzled LDS read: byte = row*256 + (bytecol ^ ((row&7)<<4))
__device__ __forceinline__ bf16x8 ldfrag(const u16* buf, int row, int kbyte){
  return *(const bf16x8*)((const char*)buf + row*256 + ((u32)kbyte ^ (u32)((row&7)<<4)));
}

// stage 128x128 bf16 tile into LDS via global_load_lds (linear dest, pre-swizzled src)
// wave wv_ fills rows [wv_*32, wv_*32+32)
__device__ __forceinline__ void stage_B(const u16* __restrict__ src, int strideElems, int colOff,
                                        u16* BsBase, int wv_, int lane){
  int rb = wv_*32 + (lane>>4);
  int slotbase = lane & 15;
  #pragma unroll
  for(int it=0; it<8; it++){
    int r = rb + it*4;
    int slot = slotbase ^ (r&7);
    __builtin_amdgcn_global_load_lds(
      (const __attribute__((address_space(1))) unsigned*)(src + (size_t)r*strideElems + colOff + slot*8),
      (__attribute__((address_space(3))) unsigned*)((char*)BsBase + wv_*8192 + it*1024),
      16, 0, 0);
  }
}

// MFMA over K=128 with A fragments in registers, B in swizzled LDS
__device__ __forceinline__ void mfma_regA(const bf16x8 af[8], const u16* Bs,
                                          int l31, int lkh, f32x16 acc[4]){
  #pragma unroll
  for(int kk=0;kk<8;kk++){
    #pragma unroll
    for(int c=0;c<4;c++){
      bf16x8 bf = ldfrag(Bs, c*32 + l31, kk*32 + lkh);
      acc[c] = MFMA32(af[kk], bf, acc[c]);
    }
  }
}

// residual(bf16) + LayerNorm epilogue -> hb
__device__ __forceinline__ void ln_epilogue(f32x16 acc[4], size_t r0, int wrow0, int l31, int h5,
    const float* g, const float* b, u16* hb){
  float gc[4], bc[4];
  #pragma unroll
  for(int c=0;c<4;c++){ int col = c*32 + l31; gc[c]=g[col]; bc[c]=b[col]; }
  #pragma unroll
  for(int r=0;r<16;r++){
    int rowl = wrow0 + (r&3) + 8*(r>>2) + 4*h5;
    size_t base = (r0 + rowl)*(size_t)D;
    float v[4];
    #pragma unroll
    for(int c=0;c<4;c++) v[c] = acc[c][r] + b2f(hb[base + c*32 + l31]);
    float s = rsum32(v[0]+v[1]+v[2]+v[3]);
    float mean = s * (1.0f/128.0f);
    float dd[4]; float q = 0.f;
    #pragma unroll
    for(int c=0;c<4;c++){ dd[c]=v[c]-mean; q += dd[c]*dd[c]; }
    q = rsum32(q);
    float rs = rsqrtf(q*(1.0f/128.0f) + 1e-5f);
    #pragma unroll
    for(int c=0;c<4;c++){
      float o = dd[c]*rs*gc[c] + bc[c];
      hb[base + c*32 + l31] = f2b(o);
    }
  }
}

// ---------------- h0 -> hb (bf16) ----------------
__global__ __launch_bounds__(256) void k_hinit(const float* __restrict__ h0, u16* __restrict__ hb){
  int i = blockIdx.x*256 + threadIdx.x;
  float4 v = ((const float4*)h0)[i];
  ushort4 p; p.x=f2b(v.x); p.y=f2b(v.y); p.z=f2b(v.z); p.w=f2b(v.w);
  ((ushort4*)hb)[i] = p;
}

// ---------------- leaf embedding + LN ----------------
__global__ __launch_bounds__(256) void k_embed(const int* __restrict__ x, const int* __restrict__ pos,
    const int* __restrict__ leaf, const float* __restrict__ emb,
    const float* __restrict__ g, const float* __restrict__ b, u16* __restrict__ hb){
  int row = blockIdx.x*4 + (threadIdx.x>>6);
  int lane = threadIdx.x & 63;
  int tok = x[row]; float p = (float)pos[row];
  float v[2];
  #pragma unroll
  for(int j=0;j<2;j++){
    int d = lane + 64*j;
    float freq = expf(-0.07195578515529633f * (float)(d & ~1));
    float ang = p * freq;
    float pe = (d&1) ? cosf(ang) : sinf(ang);
    v[j] = emb[(size_t)tok*D + d] * 11.313708498984761f + pe;
  }
  float mean = wredsum(v[0]+v[1]) * (1.0f/128.0f);
  float d0 = v[0]-mean, d1 = v[1]-mean;
  float var = wredsum(d0*d0 + d1*d1) * (1.0f/128.0f);
  float rs = rsqrtf(var + 1e-5f);
  size_t orow = (size_t)leaf[row];
  hb[orow*D + lane]      = f2b(d0*rs*g[lane]    + b[lane]);
  hb[orow*D + lane + 64] = f2b(d1*rs*g[lane+64] + b[lane+64]);
}

// ---------------- weight transpose + bf16 convert ----------------
__global__ __launch_bounds__(256) void k_wconv(const float* __restrict__ Wq, const float* __restrict__ Wk,
    const float* __restrict__ Wv, const float* __restrict__ Wo,
    const float* __restrict__ W1, const float* __restrict__ W2,
    u16* __restrict__ wqt, u16* __restrict__ wkt, u16* __restrict__ wvt, u16* __restrict__ wot,
    u16* __restrict__ w1t, u16* __restrict__ w2t){
  int e = blockIdx.x*256 + threadIdx.x;     // NLAYER*196608 total
  int l = e / 196608, r = e % 196608;
  if(r < 65536){
    int w = r >> 14, i = r & 16383;
    int n = i >> 7, k = i & 127;
    const float* src = (w==0)?Wq:(w==1)?Wk:(w==2)?Wv:Wo;
    u16* dst = (w==0)?wqt:(w==1)?wkt:(w==2)?wvt:wot;
    dst[l*16384 + n*128 + k] = f2b(src[l*16384 + k*128 + n]);
  } else if(r < 131072){
    int i = r - 65536; int n = i >> 7, k = i & 127;      // n in 0..511
    w1t[l*65536 + n*128 + k] = f2b(W1[l*65536 + k*512 + n]);
  } else {
    int i = r - 131072; int n = i >> 9, f = i & 511;     // n in 0..127
    w2t[l*65536 + n*512 + f] = f2b(W2[l*65536 + f*128 + n]);
  }
}

// ---------------- CSR build ----------------
__global__ __launch_bounds__(256) void k_count(const int* __restrict__ dst, int* __restrict__ cnt){
  int e = blockIdx.x*256 + threadIdx.x;
  atomicAdd(&cnt[dst[e]], 1);
}
__global__ __launch_bounds__(256) void k_scan1(const int* __restrict__ cnt, int* __restrict__ part,
                                               int* __restrict__ bsum){
  __shared__ int s[256];
  int tid = threadIdx.x; int i = blockIdx.x*256 + tid;
  int v = cnt[i]; s[tid]=v; __syncthreads();
  for(int off=1; off<256; off<<=1){
    int t=(tid>=off)? s[tid-off]:0; __syncthreads();
    s[tid]+=t; __syncthreads();
  }
  part[i] = s[tid]-v;
  if(tid==255) bsum[blockIdx.x] = s[255];
}
__global__ __launch_bounds__(512) void k_scan2(int* __restrict__ bsum){
  __shared__ int s[512];
  int tid = threadIdx.x;
  int v = bsum[tid]; s[tid] = v; __syncthreads();
  for(int off=1; off<512; off<<=1){
    int t = (tid>=off)? s[tid-off]:0; __syncthreads();
    s[tid] += t; __syncthreads();
  }
  bsum[tid] = s[tid] - v;
}
__global__ __launch_bounds__(256) void k_scan3(const int* __restrict__ part, const int* __restrict__ bsum,
                                               int* __restrict__ indptr, int* __restrict__ cursor){
  int i = blockIdx.x*256 + threadIdx.x;
  int v = part[i] + bsum[i>>8];
  indptr[i] = v; cursor[i] = v;
  if(i==0) indptr[NN] = ETOT;
}
__global__ __launch_bounds__(256) void k_scatter(const int* __restrict__ src, const int* __restrict__ dst,
    int* __restrict__ cursor, int* __restrict__ esrc){
  int e = blockIdx.x*256 + threadIdx.x;
  int p = atomicAdd(&cursor[dst[e]], 1);
  esrc[p] = src[e];
}

// ---------------- QKV GEMM: blockIdx.y selects weight, A-frags in registers ----------
__global__ __launch_bounds__(256,2) void k_qkv(const u16* __restrict__ hb,
    const u16* __restrict__ wqt, const u16* __restrict__ wkt, const u16* __restrict__ wvt,
    const float* __restrict__ bq, const float* __restrict__ bk, const float* __restrict__ bv,
    u16* __restrict__ qb, u16* __restrict__ kb, u16* __restrict__ vb){
  __shared__ u16 Bs[128*128];
  int tid = threadIdx.x;
  int lane = tid & 63, wv_ = tid >> 6;
  int l31 = lane & 31, h5 = lane >> 5, lkh = h5*16;
  int wrow0 = wv_*32;
  size_t r0 = (size_t)blockIdx.x * 128;
  int widx = blockIdx.y;
  const u16* wt = (widx==0)?wqt:(widx==1)?wkt:wvt;
  const float* bias = (widx==0)?bq:(widx==1)?bk:bv;
  u16* op = (widx==0)?qb:(widx==1)?kb:vb;

  stage_B(wt, D, 0, Bs, wv_, lane);
  // A fragments direct from global
  bf16x8 af[8];
  const u16* arow = hb + (r0 + wrow0 + l31)*(size_t)D + h5*8;
  #pragma unroll
  for(int kk=0;kk<8;kk++) af[kk] = *(const bf16x8*)(arow + kk*16);

  f32x16 acc[4];
  #pragma unroll
  for(int c=0;c<4;c++){
    float bb = bias[c*32+l31];
    #pragma unroll
    for(int i=0;i<16;i++) acc[c][i] = bb;
  }
  __syncthreads();
  mfma_regA(af, Bs, l31, lkh, acc);
  #pragma unroll
  for(int c=0;c<4;c++){
    int col = c*32 + l31;
    #pragma unroll
    for(int r=0;r<16;r++){
      int row = wrow0 + (r&3) + 8*(r>>2) + 4*h5;
      op[(r0+row)*(size_t)D + col] = f2b(acc[c][r]);
    }
  }
}

// ---------------- attention: one wave per node, lane = (head, edge-slot) -------------
__global__ __launch_bounds__(256,6) void k_attn(const u16* qb, const u16* __restrict__ kb,
    const u16* __restrict__ vb, const int* __restrict__ indptr, const int* __restrict__ esrc,
    u16* aggb){
  int node = blockIdx.x*4 + (threadIdx.x>>6);
  int lane = threadIdx.x & 63;
  int hd = lane >> 3, eslot = lane & 7;
  int beg = indptr[node], end = indptr[node+1];
  // q fragment (16 f32, scaled by 1/sqrt(DK))
  float qr[16];
  {
    const uint4* qp = (const uint4*)(qb + (size_t)node*D + hd*16);
    uint4 a = qp[0], b = qp[1];
    u32 w[8] = {a.x,a.y,a.z,a.w,b.x,b.y,b.z,b.w};
    #pragma unroll
    for(int i=0;i<8;i++){ qr[2*i] = blo(w[i])*0.25f; qr[2*i+1] = bhi(w[i])*0.25f; }
  }
  float m = -3.0e38f, den = 0.f;
  float acc[16];
  #pragma unroll
  for(int i=0;i<16;i++) acc[i] = 0.f;
  for(int e0=beg; e0<end; e0+=8){
    int e = e0 + eslot;
    if(e < end){
      int s = esrc[e];
      const uint4* kp = (const uint4*)(kb + (size_t)s*D + hd*16);
      uint4 k0 = kp[0], k1 = kp[1];
      const uint4* vp = (const uint4*)(vb + (size_t)s*D + hd*16);
      uint4 v0 = vp[0], v1 = vp[1];
      u32 kw[8] = {k0.x,k0.y,k0.z,k0.w,k1.x,k1.y,k1.z,k1.w};
      float p = 0.f, p2 = 0.f;
      #pragma unroll
      for(int i=0;i<8;i++){ p = fmaf(blo(kw[i]), qr[2*i], p); p2 = fmaf(bhi(kw[i]), qr[2*i+1], p2); }
      p += p2;
      float nm = fmaxf(m, p);
      float fs = __expf(m - nm);
      float w  = __expf(p - nm);
      den = den*fs + w;
      u32 vw[8] = {v0.x,v0.y,v0.z,v0.w,v1.x,v1.y,v1.z,v1.w};
      #pragma unroll
      for(int i=0;i<8;i++){
        acc[2*i]   = fmaf(acc[2*i],   fs, w*blo(vw[i]));
        acc[2*i+1] = fmaf(acc[2*i+1], fs, w*bhi(vw[i]));
      }
      m = nm;
    }
  }
  // merge 8 edge-slot lanes per head
  float mo = m;
  #pragma unroll
  for(int s=1; s<8; s<<=1){
    float m2 = __shfl_xor(m, s); float d2 = __shfl_xor(den, s);
    float nm = fmaxf(m, m2);
    den = den*__expf(m-nm) + d2*__expf(m2-nm);
    m = nm;
  }
  float scale = __expf(mo - m) / den;
  #pragma unroll
  for(int i=0;i<16;i++) acc[i] *= scale;
  #pragma unroll
  for(int s=1; s<8; s<<=1){
    #pragma unroll
    for(int i=0;i<16;i++) acc[i] += __shfl_xor(acc[i], s);
  }
  if(eslot == 0){
    u32 pk[8];
    #pragma unroll
    for(int i=0;i<8;i++) pk[i] = (u32)f2b(acc[2*i]) | ((u32)f2b(acc[2*i+1])<<16);
    uint4* dp = (uint4*)(aggb + (size_t)node*D + hd*16);
    dp[0] = make_uint4(pk[0],pk[1],pk[2],pk[3]);
    dp[1] = make_uint4(pk[4],pk[5],pk[6],pk[7]);
  }
}

// ---------------- O-proj + residual + LN1 ----------------
__global__ __launch_bounds__(256,2) void k_owo(const u16* __restrict__ aggb, const u16* __restrict__ wot,
    const float* __restrict__ bo, const float* __restrict__ g1, const float* __restrict__ b1,
    u16* hb){
  __shared__ u16 Bs[128*128];
  int tid = threadIdx.x;
  int lane = tid & 63, wv_ = tid >> 6;
  int l31 = lane & 31, h5 = lane >> 5, lkh = h5*16;
  int wrow0 = wv_*32;
  size_t r0 = (size_t)blockIdx.x * 128;
  stage_B(wot, D, 0, Bs, wv_, lane);
  bf16x8 af[8];
  const u16* arow = aggb + (r0 + wrow0 + l31)*(size_t)D + h5*8;
  #pragma unroll
  for(int kk=0;kk<8;kk++) af[kk] = *(const bf16x8*)(arow + kk*16);
  f32x16 acc[4];
  #pragma unroll
  for(int c=0;c<4;c++){
    float bb = bo[c*32+l31];
    #pragma unroll
    for(int i=0;i<16;i++) acc[c][i] = bb;
  }
  __syncthreads();
  mfma_regA(af, Bs, l31, lkh, acc);
  ln_epilogue(acc, r0, wrow0, l31, h5, g1, b1, hb);
}

// ---------------- FFN: 4 chunks of 128 over DFF, fused relu + residual + LN2 ----------
__global__ __launch_bounds__(256,2) void k_ffn(const u16* __restrict__ w1t, const u16* __restrict__ w2t,
    const float* __restrict__ b1, const float* __restrict__ b2,
    const float* __restrict__ g2, const float* __restrict__ bb2,
    u16* hb){
  __shared__ u16 Bs[128*128];
  __shared__ u16 Ts[128*128];
  int tid = threadIdx.x;
  int lane = tid & 63, wv_ = tid >> 6;
  int l31 = lane & 31, h5 = lane >> 5, lkh = h5*16;
  int wrow0 = wv_*32;
  size_t r0 = (size_t)blockIdx.x * 128;
  bf16x8 af[8];
  const u16* arow = hb + (r0 + wrow0 + l31)*(size_t)D + h5*8;
  #pragma unroll
  for(int kk=0;kk<8;kk++) af[kk] = *(const bf16x8*)(arow + kk*16);
  f32x16 out[4];
  #pragma unroll
  for(int c=0;c<4;c++){
    float bb = b2[c*32+l31];
    #pragma unroll
    for(int i=0;i<16;i++) out[c][i] = bb;
  }
  for(int ch=0; ch<4; ch++){
    if(ch) __syncthreads();                         // prev mfma2 done reading Bs/Ts
    stage_B(w1t + ch*128*D, D, 0, Bs, wv_, lane);
    __syncthreads();
    f32x16 tacc[4];
    #pragma unroll
    for(int c=0;c<4;c++){
      float bb = b1[ch*128 + c*32 + l31];
      #pragma unroll
      for(int i=0;i<16;i++) tacc[c][i] = bb;
    }
    mfma_regA(af, Bs, l31, lkh, tacc);
    #pragma unroll
    for(int c=0;c<4;c++){
      int tcol = c*32 + l31;
      #pragma unroll
      for(int r=0;r<16;r++){
        int trow = wrow0 + (r&3) + 8*(r>>2) + 4*h5;
        *(u16*)((char*)Ts + trow*256 + (u32)((tcol*2) ^ ((trow&7)<<4))) = f2b(fmaxf(tacc[c][r],0.f));
      }
    }
    __syncthreads();                                // Ts written, Bs free
    stage_B(w2t, DFF, ch*128, Bs, wv_, lane);
    __syncthreads();
    bf16x8 taf[8];
    #pragma unroll
    for(int kk=0;kk<8;kk++) taf[kk] = ldfrag(Ts, wrow0 + l31, kk*32 + lkh);
    mfma_regA(taf, Bs, l31, lkh, out);
  }
  ln_epilogue(out, r0, wrow0, l31, h5, g2, bb2, hb);
}

// ---------------- readout ----------------
__global__ __launch_bounds__(64) void k_readout(const u16* __restrict__ hb, const int* __restrict__ rid,
    const float* __restrict__ gw, const float* __restrict__ gb, float* __restrict__ out){
  int r = blockIdx.x; int lane = threadIdx.x;
  size_t node = (size_t)rid[r];
  float h0v = b2f(hb[node*D + lane]), h1v = b2f(hb[node*D + 64 + lane]);
  float lg[NCLS];
  #pragma unroll
  for(int c=0;c<NCLS;c++){
    float p = h0v*gw[lane*NCLS + c] + h1v*gw[(lane+64)*NCLS + c];
    lg[c] = wredsum(p) + gb[c];
  }
  float mx = lg[0];
  #pragma unroll
  for(int c=1;c<NCLS;c++) mx = fmaxf(mx, lg[c]);
  float se = 0.f;
  #pragma unroll
  for(int c=0;c<NCLS;c++) se += expf(lg[c]-mx);
  float lse = mx + logf(se);
  if(lane < NCLS) out[(size_t)r*NCLS + lane] = lg[lane] - lse;
}

extern "C" void kernel_launch(void* const* d_in, const int* in_sizes, int n_in,
                              void* d_out, int out_size, void* d_ws, size_t ws_size,
                              hipStream_t stream) {
  const int* x    = (const int*)d_in[0];
  const int* pos  = (const int*)d_in[1];
  const int* leaf = (const int*)d_in[2];
  const int* src  = (const int*)d_in[3];
  const int* dst  = (const int*)d_in[4];
  const int* rid  = (const int*)d_in[5];
  const float* h0 = (const float*)d_in[6];
  const float* emb= (const float*)d_in[7];
  const float* eng= (const float*)d_in[8];
  const float* enb= (const float*)d_in[9];
  const float* Wq = (const float*)d_in[10];
  const float* bq = (const float*)d_in[11];
  const float* Wk = (const float*)d_in[12];
  const float* bk = (const float*)d_in[13];
  const float* Wv = (const float*)d_in[14];
  const float* bv = (const float*)d_in[15];
  const float* Wo = (const float*)d_in[16];
  const float* bo = (const float*)d_in[17];
  const float* l1g= (const float*)d_in[18];
  const float* l1b= (const float*)d_in[19];
  const float* W1 = (const float*)d_in[20];
  const float* b1 = (const float*)d_in[21];
  const float* W2 = (const float*)d_in[22];
  const float* b2 = (const float*)d_in[23];
  const float* l2g= (const float*)d_in[24];
  const float* l2b= (const float*)d_in[25];
  const float* gw = (const float*)d_in[26];
  const float* gb = (const float*)d_in[27];
  float* out = (float*)d_out;

  char* ws = (char*)d_ws;
  u16* hb     = (u16*)(ws);                          // 33,554,432
  u16* qb     = (u16*)(ws + 33554432);               // 33,554,432 (agg aliases)
  u16* kb     = (u16*)(ws + 67108864);               // 33,554,432
  u16* vb     = (u16*)(ws + 100663296);              // 33,554,432
  u16* wqt    = (u16*)(ws + 134217728);              // 131,072
  u16* wkt    = (u16*)(ws + 134348800);
  u16* wvt    = (u16*)(ws + 134479872);
  u16* wot    = (u16*)(ws + 134610944);
  u16* w1t    = (u16*)(ws + 134742016);              // 524,288
  u16* w2t    = (u16*)(ws + 135266304);              // 524,288
  int* indptr = (int*)(ws + 135790592);              // 524,544
  int* cursor = (int*)(ws + 136315136);              // 524,288
  int* part   = (int*)(ws + 136839424);              // 524,288
  int* bsum   = (int*)(ws + 137363712);              // 2,048
  int* esrc   = (int*)(ws + 137365760);              // 2,621,440  -> ~140 MB total

  k_hinit<<<NN*D/4/256, 256, 0, stream>>>(h0, hb);
  k_embed<<<NLEAF/4, 256, 0, stream>>>(x, pos, leaf, emb, eng, enb, hb);
  k_wconv<<<NLAYER*196608/256, 256, 0, stream>>>(Wq,Wk,Wv,Wo,W1,W2, wqt,wkt,wvt,wot,w1t,w2t);

  hipMemsetAsync(cursor, 0, NN*sizeof(int), stream);
  k_count  <<<ETOT/256, 256, 0, stream>>>(dst, cursor);
  k_scan1  <<<NN/256, 256, 0, stream>>>(cursor, part, bsum);
  k_scan2  <<<1, 512, 0, stream>>>(bsum);
  k_scan3  <<<NN/256, 256, 0, stream>>>(part, bsum, indptr, cursor);
  k_scatter<<<ETOT/256, 256, 0, stream>>>(src, dst, cursor, esrc);

  for(int l=0; l<NLAYER; l++){
    k_qkv<<<dim3(NN/128,3), 256, 0, stream>>>(hb, wqt + l*16384, wkt + l*16384, wvt + l*16384,
                                              bq + l*D, bk + l*D, bv + l*D, qb, kb, vb);
    k_attn<<<NN/4, 256, 0, stream>>>(qb, kb, vb, indptr, esrc, qb);
    k_owo<<<NN/128, 256, 0, stream>>>(qb, wot + l*16384, bo + l*D,
                                      l1g + l*D, l1b + l*D, hb);
    k_ffn<<<NN/128, 256, 0, stream>>>(w1t + l*65536, w2t + l*65536,
                                      b1 + l*DFF, b2 + l*D, l2g + l*D, l2b + l*D, hb);
  }
  k_readout<<<NREAD, 64, 0, stream>>>(hb, rid, gw, gb, out);
}